// Round 1
// 252.187 us; speedup vs baseline: 1.0906x; 1.0906x over previous
//
#include <hip/hip_runtime.h>

#define F_IN  512
#define F_OUT 128
#define FBIN  32            // nodes per fine bin
#define EPB   4096          // edges per fill partition block
#define C2MAX 1600          // max fine bins (N <= 51200)
#define CAPF  2048          // slab capacity per bin (mean ~1024, ~32 sigma headroom)

typedef __attribute__((ext_vector_type(8))) short  short8;
typedef __attribute__((ext_vector_type(4))) float  floatx4;

__device__ __forceinline__ unsigned short f2bf(float f) {
    unsigned u = __float_as_uint(f);
    return (unsigned short)((u + 0x7FFF + ((u >> 16) & 1)) >> 16);  // RNE
}
__device__ __forceinline__ float bf2f(unsigned b) {
    return __uint_as_float(b << 16);
}

// ---------------------------------------------------------------------------
// prep: blocks 0..127 transpose-convert w fp32 [512][128] -> wt bf16 [128][512];
// blocks 128.. zero the per-bin cursors. Replaces hist_convert+scan+memset.
// ---------------------------------------------------------------------------
__global__ __launch_bounds__(256) void prep(
    const float* __restrict__ w, unsigned short* __restrict__ wt,
    int* __restrict__ cursor, int C2)
{
    const int tid = threadIdx.x;
    if ((int)blockIdx.x < 128) {
        int g0 = blockIdx.x * 512 + tid;
        #pragma unroll
        for (int r = 0; r < 2; ++r) {
            int gid = g0 + r * 256;
            int n = gid >> 9, k = gid & 511;
            wt[gid] = f2bf(w[(size_t)k * F_OUT + n]);
        }
    } else {
        int c = ((int)blockIdx.x - 128) * 256 + tid;
        if (c < C2) cursor[c] = 0;
    }
}

// ---------------------------------------------------------------------------
// fill_gemm: blocks 0..FB-1 = fill (LDS rank + one batched cursor claim per
// fine 32-node bin -> direct append into fixed-capacity slabs, no scan);
// blocks FB.. = MFMA GEMM h = bf16(x) @ wt (unchanged proven structure).
// Fill LDS (2x1600 ints) unioned with GEMM LDS (sa+sb) -> 26.1 KB.
// ---------------------------------------------------------------------------
__global__ __launch_bounds__(256, 2) void fill_gemm(
    const int* __restrict__ ei, const float* __restrict__ ew,
    int* __restrict__ cursor, uint2* __restrict__ ent, int E, int C2, int FB,
    const float* __restrict__ x, const unsigned short* __restrict__ wt,
    unsigned short* __restrict__ h, int N)
{
    __shared__ __align__(16) char smem[(64 * 68 + 128 * 68) * 2];  // 26112 B
    const int tid = threadIdx.x;

    if ((int)blockIdx.x < FB) {
        // ----- fill -----
        int* lh    = (int*)smem;            // [C2MAX]
        int* lbase = (int*)smem + C2MAX;    // [C2MAX]
        for (int c = tid; c < C2; c += 256) lh[c] = 0;
        __syncthreads();

        const int base = blockIdx.x * EPB;
        unsigned       mykey[EPB / 256];
        unsigned char  mydl[EPB / 256];
        short          mybin[EPB / 256];
        unsigned short myrank[EPB / 256];

        #pragma unroll
        for (int j = 0; j < EPB / 256; ++j) {
            int e = base + j * 256 + tid;
            mybin[j] = -1;
            if (e < E) {
                int   src = ei[e];
                int   dst = ei[E + e];
                float w   = ew[e];
                int bin = dst >> 5;                       // 32-node fine bin
                mykey[j]  = (unsigned)src | ((unsigned)f2bf(w) << 16);
                mydl[j]   = (unsigned char)(dst & (FBIN - 1));
                mybin[j]  = (short)bin;
                myrank[j] = (unsigned short)atomicAdd(&lh[bin], 1);
            }
        }
        __syncthreads();
        for (int c = tid; c < C2; c += 256)
            if (lh[c] > 0) lbase[c] = atomicAdd(&cursor[c], lh[c]);
        __syncthreads();
        #pragma unroll
        for (int j = 0; j < EPB / 256; ++j) {
            if (mybin[j] >= 0) {
                int o = lbase[mybin[j]] + myrank[j];
                if (o < CAPF)                              // overflow -> drop, slow path covers
                    ent[(size_t)(int)mybin[j] * CAPF + o] = make_uint2(mykey[j], mydl[j]);
            }
        }
        return;
    }

    // ----- GEMM -----
    unsigned short* sa = (unsigned short*)smem;       // [64][68]
    unsigned short* sb = sa + 64 * 68;                // [128][68]

    const int wave = tid >> 6, lane = tid & 63;
    const int g    = lane >> 4, l16 = lane & 15;
    const int m0   = ((int)blockIdx.x - FB) * 64;

    const int arow = tid >> 2, aq = tid & 3;
    const int brow = tid >> 1, bh = tid & 1;

    floatx4 acc[8];
    #pragma unroll
    for (int i = 0; i < 8; ++i) acc[i] = (floatx4)(0.f);

    const bool  avalid = (m0 + arow) < N;
    const float* xp = x + (size_t)(m0 + arow) * F_IN + aq * 16;
    const unsigned short* bp = wt + brow * F_IN + bh * 32;

    float4 ax[4];
    uint4  bv[4];
    #pragma unroll
    for (int i = 0; i < 4; ++i) ax[i] = make_float4(0.f, 0.f, 0.f, 0.f);
    if (avalid) {
        #pragma unroll
        for (int i = 0; i < 4; ++i) ax[i] = ((const float4*)xp)[i];
    }
    #pragma unroll
    for (int i = 0; i < 4; ++i) bv[i] = ((const uint4*)bp)[i];

    for (int s = 0; s < 8; ++s) {
        __syncthreads();
        #pragma unroll
        for (int i = 0; i < 4; ++i) {
            ushort4 t;
            t.x = f2bf(ax[i].x); t.y = f2bf(ax[i].y);
            t.z = f2bf(ax[i].z); t.w = f2bf(ax[i].w);
            *(ushort4*)&sa[arow * 68 + aq * 16 + i * 4] = t;
        }
        #pragma unroll
        for (int i = 0; i < 4; ++i) {
            *(uint2*)&sb[brow * 68 + bh * 32 + i * 8]     = make_uint2(bv[i].x, bv[i].y);
            *(uint2*)&sb[brow * 68 + bh * 32 + i * 8 + 4] = make_uint2(bv[i].z, bv[i].w);
        }
        if (s < 7) {
            int k0n = (s + 1) * 64;
            if (avalid) {
                #pragma unroll
                for (int i = 0; i < 4; ++i) ax[i] = ((const float4*)(xp + k0n))[i];
            }
            #pragma unroll
            for (int i = 0; i < 4; ++i) bv[i] = ((const uint4*)(bp + k0n))[i];
        }
        __syncthreads();

        #pragma unroll
        for (int kc = 0; kc < 2; ++kc) {
            union { ushort4 u[2]; short8 v; } af;
            int abase = (wave * 16 + l16) * 68 + kc * 32 + g * 8;
            af.u[0] = *(ushort4*)&sa[abase];
            af.u[1] = *(ushort4*)&sa[abase + 4];
            #pragma unroll
            for (int nt = 0; nt < 8; ++nt) {
                union { ushort4 u[2]; short8 v; } bf;
                int bbase = (nt * 16 + l16) * 68 + kc * 32 + g * 8;
                bf.u[0] = *(ushort4*)&sb[bbase];
                bf.u[1] = *(ushort4*)&sb[bbase + 4];
                acc[nt] = __builtin_amdgcn_mfma_f32_16x16x32_bf16(af.v, bf.v, acc[nt], 0, 0, 0);
            }
        }
    }

    #pragma unroll
    for (int nt = 0; nt < 8; ++nt) {
        #pragma unroll
        for (int r = 0; r < 4; ++r) {
            int row = m0 + wave * 16 + g * 4 + r;
            if (row < N) h[(size_t)row * F_OUT + nt * 16 + l16] = f2bf(acc[nt][r]);
        }
    }
}

// ---------------------------------------------------------------------------
// fine_agg: one block per 32-node fine bin (no dst filtering). Two passes
// over the bin's slab: 32-bin hist+scan, then place keys node-sorted into
// LDS. Wave per 8 nodes; half-wave per edge parity; lane = 4 feats;
// shfl_xor(32) reduce; fused bias+relu float4 writeout.
// ---------------------------------------------------------------------------
__global__ __launch_bounds__(256) void fine_agg(
    const unsigned short* __restrict__ h, const uint2* __restrict__ ent,
    const int* __restrict__ cursor, const float* __restrict__ bias,
    float* __restrict__ out, int N, int E,
    const int* __restrict__ ei, const float* __restrict__ ew)
{
    __shared__ unsigned ssort[CAPF];          // 8 KB
    __shared__ int lh[FBIN], lcur[FBIN];
    __shared__ int sso[FBIN + 1];

    const int b    = blockIdx.x;
    const int tid  = threadIdx.x;
    const int wave = tid >> 6;
    const int lane = tid & 63;
    const int half = lane >> 5;               // edge parity
    const int q    = lane & 31;               // feats q*4 .. q*4+3
    const float4 bv = *(const float4*)&bias[q * 4];
    const int raw  = cursor[b];
    const int cnt  = raw < CAPF ? raw : CAPF;
    const uint2* slab = ent + (size_t)b * CAPF;

    if (tid < FBIN) lh[tid] = 0;
    __syncthreads();

    for (int i = tid; i < cnt; i += 256)
        atomicAdd(&lh[(int)slab[i].y], 1);
    __syncthreads();

    if (wave == 0 && lane < FBIN) {
        int v = lh[lane];
        int orig = v;
        #pragma unroll
        for (int off = 1; off < FBIN; off <<= 1) {
            int t = __shfl_up(v, off);
            if (lane >= off) v += t;
        }
        sso[lane]  = v - orig;
        lcur[lane] = v - orig;
        if (lane == FBIN - 1) sso[FBIN] = v;
    }
    __syncthreads();

    if (raw <= CAPF) {
        for (int i = tid; i < cnt; i += 256) {
            uint2 e = slab[i];
            int r = atomicAdd(&lcur[(int)e.y], 1);
            ssort[r] = e.x;
        }
        __syncthreads();

        #pragma unroll 1
        for (int t = 0; t < 8; ++t) {
            int nd   = wave * 8 + t;
            int node = b * FBIN + nd;
            int s = sso[nd], e2 = sso[nd + 1];
            float4 acc = make_float4(0.f, 0.f, 0.f, 0.f);
            for (int i = s; i < e2; i += 8) {
                #pragma unroll
                for (int j = 0; j < 4; ++j) {
                    int idx = i + j * 2 + half;
                    unsigned bk = 0;
                    if (idx < e2) bk = ssort[idx];
                    float wgt = bf2f(bk >> 16);
                    uint2 hv = *(const uint2*)&h[(size_t)(bk & 0xFFFF) * F_OUT + q * 4];
                    acc.x += bf2f(hv.x & 0xFFFF) * wgt;
                    acc.y += bf2f(hv.x >> 16)    * wgt;
                    acc.z += bf2f(hv.y & 0xFFFF) * wgt;
                    acc.w += bf2f(hv.y >> 16)    * wgt;
                }
            }
            acc.x += __shfl_xor(acc.x, 32);
            acc.y += __shfl_xor(acc.y, 32);
            acc.z += __shfl_xor(acc.z, 32);
            acc.w += __shfl_xor(acc.w, 32);
            if (half == 0 && node < N) {
                float4 o;
                o.x = fmaxf(acc.x + bv.x, 0.f);
                o.y = fmaxf(acc.y + bv.y, 0.f);
                o.z = fmaxf(acc.z + bv.z, 0.f);
                o.w = fmaxf(acc.w + bv.w, 0.f);
                *(float4*)&out[(size_t)node * F_OUT + q * 4] = o;
            }
        }
    } else {
        // slab overflow (never expected at this E/N): correct-but-slow path
        // over the raw edge list.
        #pragma unroll 1
        for (int t = 0; t < 8; ++t) {
            int nd   = wave * 8 + t;
            int node = b * FBIN + nd;
            float4 acc = make_float4(0.f, 0.f, 0.f, 0.f);
            for (int e = half; e < E; e += 2) {
                if (ei[E + e] == node) {
                    float wgt = ew[e];
                    uint2 hv = *(const uint2*)&h[(size_t)ei[e] * F_OUT + q * 4];
                    acc.x += bf2f(hv.x & 0xFFFF) * wgt;
                    acc.y += bf2f(hv.x >> 16)    * wgt;
                    acc.z += bf2f(hv.y & 0xFFFF) * wgt;
                    acc.w += bf2f(hv.y >> 16)    * wgt;
                }
            }
            acc.x += __shfl_xor(acc.x, 32);
            acc.y += __shfl_xor(acc.y, 32);
            acc.z += __shfl_xor(acc.z, 32);
            acc.w += __shfl_xor(acc.w, 32);
            if (half == 0 && node < N) {
                float4 o;
                o.x = fmaxf(acc.x + bv.x, 0.f);
                o.y = fmaxf(acc.y + bv.y, 0.f);
                o.z = fmaxf(acc.z + bv.z, 0.f);
                o.w = fmaxf(acc.w + bv.w, 0.f);
                *(float4*)&out[(size_t)node * F_OUT + q * 4] = o;
            }
        }
    }
}

static inline size_t align256(size_t x) { return (x + 255) & ~(size_t)255; }

extern "C" void kernel_launch(void* const* d_in, const int* in_sizes, int n_in,
                              void* d_out, int out_size, void* d_ws, size_t ws_size,
                              hipStream_t stream)
{
    const float* x    = (const float*)d_in[0];   // [N, 512]
    const int*   ei   = (const int*)  d_in[1];   // [2, E] int32
    const float* ew   = (const float*)d_in[2];   // [E]
    const float* w    = (const float*)d_in[3];   // [512, 128]
    const float* bias = (const float*)d_in[4];   // [128]
    float*       out  = (float*)d_out;           // [N, 128]

    const int N  = in_sizes[0] / F_IN;           // 50000
    const int E  = in_sizes[2];                  // 1600000
    const int C2 = (N + FBIN - 1) / FBIN;        // 1563 fine bins

    // workspace layout (~38.6 MB)
    char*  ws = (char*)d_ws;
    size_t off = 0;
    unsigned short* h      = (unsigned short*)(ws + off); off += align256((size_t)N * F_OUT * 2);
    unsigned short* wt     = (unsigned short*)(ws + off); off += align256((size_t)F_OUT * F_IN * 2);
    int*            cursor = (int*)(ws + off);            off += align256((size_t)C2 * 4);
    uint2*          ent    = (uint2*)(ws + off);          off += align256((size_t)C2 * CAPF * 8);

    const int FB = (E + EPB - 1) / EPB;          // 391 fill blocks
    const int GB = (N + 63) / 64;                // 782 gemm blocks
    const int ZB = (C2 + 255) / 256;             // 7 cursor-zero blocks

    prep<<<128 + ZB, 256, 0, stream>>>(w, wt, cursor, C2);
    fill_gemm<<<FB + GB, 256, 0, stream>>>(ei, ew, cursor, ent, E, C2, FB,
                                           x, wt, h, N);
    fine_agg<<<C2, 256, 0, stream>>>(h, ent, cursor, bias, out, N, E, ei, ew);
}